// Round 5
// baseline (599.832 us; speedup 1.0000x reference)
//
#include <hip/hip_runtime.h>
#include <math.h>

#define LRELU(v) ((v) > 0.0f ? (v) : 0.02f * (v))

typedef __attribute__((ext_vector_type(8)))  short short8;   // 8 bf16 / 4 VGPRs
typedef __attribute__((ext_vector_type(4)))  float f32x4;
typedef __attribute__((ext_vector_type(16))) float f32x16;
typedef __attribute__((ext_vector_type(2)))  int   int2v;
typedef __attribute__((ext_vector_type(4)))  int   int4v;

__device__ inline short f2bf(float f) {                       // RNE (weights only)
    unsigned u = __builtin_bit_cast(unsigned, f);
    unsigned r = (u + 0x7FFFu + ((u >> 16) & 1u)) >> 16;
    return (short)r;
}
__device__ inline short bftrunc(float f) {                    // truncate
    return (short)(__builtin_bit_cast(unsigned, f) >> 16);
}
__device__ inline int pack2_trunc(float lo, float hi) {       // lo->low16, hi->high16
    unsigned a = __builtin_bit_cast(unsigned, lo);
    unsigned b = __builtin_bit_cast(unsigned, hi);
    return (int)((b & 0xFFFF0000u) | (a >> 16));
}
__device__ inline float bflo(unsigned u) { return __builtin_bit_cast(float, u << 16); }
__device__ inline float bfhi(unsigned u) { return __builtin_bit_cast(float, u & 0xFFFF0000u); }

#define PAIRS 8
#define NP1   2
#define RS5   0.44721359549995793f   // 1/sqrt(5)

// ---------------------------------------------------------------------------
// Kernel 1: second-hop graph layer. MFMA P1/P2 + MFMA scores; branchless
// Phase-B scatter with per-lane precomputed LDS indices; RS5 folded into k
// weight fragments; truncation bf16 packing throughout the data path.
// ---------------------------------------------------------------------------
__global__ __launch_bounds__(256, 4) void gl2_kernel(
    const float* __restrict__ x2,
    const float* __restrict__ lw, const float* __restrict__ lb,
    const float* __restrict__ iw, const float* __restrict__ ib,
    const float* __restrict__ ow, const float* __restrict__ ob,
    float* __restrict__ h1out)
{
    __shared__ short y_lds[32][40];        // y bf16
    __shared__ short qk[2 * 6 * 33 * 8];   // [qk][h][row][e]: q=0..,k=6.., row32=0, e>=5=0
    __shared__ float vT[6][5][36];         // v fp32 [h][e][t]; cols 32..35 = dump pad
    __shared__ short att2[6][32][40];      // att bf16 [h][s][t]
    __shared__ float abar[6][32];
    __shared__ float obar[32];

    const int tid  = threadIdx.x;
    const int lane = tid & 63;
    const int w    = tid >> 6;
    const int l15  = lane & 15;
    const int lq   = lane >> 4;
    const int h5   = lane >> 5;
    const int scol = lane & 31;
    const int rowz = (lane < 32) ? scol : 32;

    for (int i = tid; i < (2 * 6 * 33 * 8) / 2; i += 256) ((int*)qk)[i] = 0;
    if (tid < 2) obar[30 + tid] = 0.0f;

    // ---- persistent fragments & scatter metadata (once per block) ----
    const int di = w & 1, si = w >> 1;
    short8 blw; float lbv;
    {
        int d = di * 16 + l15;
        #pragma unroll
        for (int i = 0; i < 8; ++i) {
            int k = lq * 8 + i;
            blw[i] = f2bf((d < 30 && k < 30) ? lw[d * 30 + k] : 0.0f);
        }
        lbv = (d < 30) ? lb[d] : 0.0f;
    }
    short8 bfr[3]; float sc_bias[3]; int sc_idx[3]; bool sc_isv[3]; bool useA1[3];
    #pragma unroll
    for (int t = 0; t < 3; ++t) {
        int T = 3 * w + t, jt = T >> 1;
        int j = jt * 16 + l15;
        int s0 = (T & 1) * 16 + lq * 4;
        useA1[t] = (T & 1) != 0;
        float scale = (j >= 30 && j < 60) ? RS5 : 1.0f;
        short8 f;
        #pragma unroll
        for (int i = 0; i < 8; ++i) {
            int k = lq * 8 + i;
            f[i] = f2bf((j < 90 && k < 30) ? iw[j * 30 + k] * scale : 0.0f);
        }
        bfr[t] = f;
        sc_bias[t] = (j < 90) ? ib[j] * scale : 0.0f;
        sc_isv[t] = (jt >= 4);
        if (j < 30) {
            int h = j / 5, e = j - 5 * h;
            sc_idx[t] = (h * 33 + s0) * 8 + e;                 // q, stride r: +8
        } else if (j < 60) {
            int jj = j - 30; int h = jj / 5, e = jj - 5 * h;
            sc_idx[t] = ((6 + h) * 33 + s0) * 8 + e;           // k, stride r: +8
        } else if (j < 90) {
            int jj = j - 60; int h = jj / 5, e = jj - 5 * h;
            sc_idx[t] = (h * 5 + e) * 36 + s0;                 // v (float idx), stride r: +1
        } else {
            sc_idx[t] = ((l15 - 10) * 5) * 36 + 33;            // dump into vT padding
        }
    }
    float* vbase = &vT[0][0][0];
    __syncthreads();

    for (int p = 0; p < PAIRS; ++p) {
        const long pair = (long)blockIdx.x * PAIRS + p;
        const float* xp = x2 + pair * 960;

        // ---- Phase A: x -> y (1 mfma), trunc-packed input, y -> LDS bf16 ----
        {
            float xv[8];
            int s = si * 16 + l15;
            #pragma unroll
            for (int i = 0; i < 8; ++i) {
                int k = lq * 8 + i;
                xv[i] = (k < 30) ? xp[s * 30 + k] : 0.0f;
            }
            int4v pk = { pack2_trunc(xv[0], xv[1]), pack2_trunc(xv[2], xv[3]),
                         pack2_trunc(xv[4], xv[5]), pack2_trunc(xv[6], xv[7]) };
            short8 af = __builtin_bit_cast(short8, pk);
            f32x4 c = {0.0f, 0.0f, 0.0f, 0.0f};
            c = __builtin_amdgcn_mfma_f32_16x16x32_bf16(af, blw, c, 0, 0, 0);
            #pragma unroll
            for (int r = 0; r < 4; ++r) {
                float yv = c[r] + lbv;
                yv = LRELU(yv);
                y_lds[si * 16 + lq * 4 + r][di * 16 + l15] = bftrunc(yv);
            }
        }
        __syncthreads();

        // ---- Phase B: qkv (3 mfma/wave), branchless precomputed scatter ----
        {
            short8 a0 = *(const short8*)&y_lds[l15][lq * 8];
            short8 a1 = *(const short8*)&y_lds[16 + l15][lq * 8];
            #pragma unroll
            for (int t = 0; t < 3; ++t) {
                short8 a = useA1[t] ? a1 : a0;
                f32x4 c = {0.0f, 0.0f, 0.0f, 0.0f};
                c = __builtin_amdgcn_mfma_f32_16x16x32_bf16(a, bfr[t], c, 0, 0, 0);
                float bias = sc_bias[t];
                if (!sc_isv[t]) {
                    short* pp = qk + sc_idx[t];
                    #pragma unroll
                    for (int r = 0; r < 4; ++r) pp[r * 8] = bftrunc(c[r] + bias);
                } else {
                    float* pp = vbase + sc_idx[t];
                    #pragma unroll
                    for (int r = 0; r < 4; ++r) pp[r] = c[r] + bias;
                }
            }
        }
        __syncthreads();

        // ---- Phase C: per-head scores via MFMA 32x32x16 + softmax in C-layout ----
        if (w < 3) {
            #pragma unroll
            for (int hh = 0; hh < 2; ++hh) {
                const int h = 2 * w + hh;
                short8 af = *(const short8*)&qk[((6 + h) * 33 + rowz) * 8];  // K
                short8 bf = *(const short8*)&qk[(h * 33 + rowz) * 8];        // Q^T
                f32x16 c;
                #pragma unroll
                for (int r = 0; r < 16; ++r) c[r] = 0.0f;
                c = __builtin_amdgcn_mfma_f32_32x32x16_bf16(af, bf, c, 0, 0, 0);
                float m = c[0];
                #pragma unroll
                for (int r = 1; r < 16; ++r) m = fmaxf(m, c[r]);
                m = fmaxf(m, __shfl_xor(m, 32));
                float Z = 0.0f;
                #pragma unroll
                for (int r = 0; r < 16; ++r) { c[r] = __expf(c[r] - m); Z += c[r]; }
                Z += __shfl_xor(Z, 32);
                float rZ = (1.0f / 32.0f) / Z;
                #pragma unroll
                for (int g = 0; g < 4; ++g) {
                    int tb = 8 * g + 4 * h5;
                    int2v wv;
                    wv.x = pack2_trunc(c[4 * g] * rZ, c[4 * g + 1] * rZ);
                    wv.y = pack2_trunc(c[4 * g + 2] * rZ, c[4 * g + 3] * rZ);
                    *(int2v*)&att2[h][scol][tb] = wv;
                }
            }
        }
        __syncthreads();

        // ---- Phase D: abar via b32 pair reads (96 threads, 2 t's each) ----
        if (tid < 96) {
            const int h = tid >> 4, tp = tid & 15;
            const short* cp = &att2[h][0][2 * tp];
            float s0 = 0.0f, s1 = 0.0f;
            #pragma unroll
            for (int s = 0; s < 32; ++s) {
                unsigned u = *(const unsigned*)(cp + s * 40);
                s0 += bflo(u);
                s1 += bfhi(u);
            }
            abar[h][2 * tp] = s0;
            abar[h][2 * tp + 1] = s1;
        }
        __syncthreads();

        // ---- Phase E: obar ----
        if (tid < 240) {
            const int he = tid >> 3, tq = tid & 7;
            const int h = he / 5, e = he - 5 * h;
            f32x4 av = *(const f32x4*)&abar[h][tq * 4];
            f32x4 vv = *(const f32x4*)&vT[h][e][tq * 4];
            float part = av.x * vv.x + av.y * vv.y + av.z * vv.z + av.w * vv.w;
            part += __shfl_down(part, 4, 8);
            part += __shfl_down(part, 2, 8);
            part += __shfl_down(part, 1, 8);
            if (tq == 0) obar[he] = part;
        }
        __syncthreads();

        // ---- Phase F: h1 = obar @ ow^T + ob ----
        if (tid < 240) {
            const int d = tid >> 3, jq = tid & 7;
            f32x4 ov = *(const f32x4*)&obar[jq * 4];
            float part = 0.0f;
            #pragma unroll
            for (int i = 0; i < 4; ++i) {
                int j = jq * 4 + i;
                if (j < 30) part = fmaf(ov[i], ow[d * 30 + j], part);
            }
            part += __shfl_down(part, 4, 8);
            part += __shfl_down(part, 2, 8);
            part += __shfl_down(part, 1, 8);
            if (jq == 0) h1out[pair * 30 + d] = part + ob[d];
        }
    }
}

// ---------------------------------------------------------------------------
// Kernel 2: first-hop layer (S=17 padded to 32, masked) + fused MLP.
// ---------------------------------------------------------------------------
__global__ __launch_bounds__(256, 4) void gl1_mlp_kernel(
    const float* __restrict__ h1, const float* __restrict__ self_feat,
    const float* __restrict__ lw, const float* __restrict__ lb,
    const float* __restrict__ iw, const float* __restrict__ ib,
    const float* __restrict__ ow, const float* __restrict__ ob,
    const float* __restrict__ cw1, const float* __restrict__ cb1,
    const float* __restrict__ cw2, const float* __restrict__ cb2,
    const float* __restrict__ cw3, const float* __restrict__ cb3,
    float* __restrict__ out)
{
    __shared__ short y_lds[32][40];
    __shared__ short qk[2 * 6 * 33 * 8];
    __shared__ float vT[6][5][36];
    __shared__ short att2[6][32][40];
    __shared__ float abar[6][32];
    __shared__ float obar[32];
    __shared__ float embb[32];
    __shared__ float hb1[64];
    __shared__ float hb2[64];
    __shared__ float lg[2];

    const int tid  = threadIdx.x;
    const int lane = tid & 63;
    const int w    = tid >> 6;
    const int l15  = lane & 15;
    const int lq   = lane >> 4;
    const int h5   = lane >> 5;
    const int scol = lane & 31;
    const int rowz = (lane < 32) ? scol : 32;

    for (int i = tid; i < (2 * 6 * 33 * 8) / 2; i += 256) ((int*)qk)[i] = 0;
    if (tid < 2) obar[30 + tid] = 0.0f;

    const int di = w & 1, si = w >> 1;
    short8 blw; float lbv;
    {
        int d = di * 16 + l15;
        #pragma unroll
        for (int i = 0; i < 8; ++i) {
            int k = lq * 8 + i;
            blw[i] = f2bf((d < 30 && k < 30) ? lw[d * 30 + k] : 0.0f);
        }
        lbv = (d < 30) ? lb[d] : 0.0f;
    }
    short8 bfr[3]; float sc_bias[3]; int sc_idx[3]; bool sc_isv[3]; bool useA1[3];
    #pragma unroll
    for (int t = 0; t < 3; ++t) {
        int T = 3 * w + t, jt = T >> 1;
        int j = jt * 16 + l15;
        int s0 = (T & 1) * 16 + lq * 4;
        useA1[t] = (T & 1) != 0;
        float scale = (j >= 30 && j < 60) ? RS5 : 1.0f;
        short8 f;
        #pragma unroll
        for (int i = 0; i < 8; ++i) {
            int k = lq * 8 + i;
            f[i] = f2bf((j < 90 && k < 30) ? iw[j * 30 + k] * scale : 0.0f);
        }
        bfr[t] = f;
        sc_bias[t] = (j < 90) ? ib[j] * scale : 0.0f;
        sc_isv[t] = (jt >= 4);
        if (j < 30) {
            int h = j / 5, e = j - 5 * h;
            sc_idx[t] = (h * 33 + s0) * 8 + e;
        } else if (j < 60) {
            int jj = j - 30; int h = jj / 5, e = jj - 5 * h;
            sc_idx[t] = ((6 + h) * 33 + s0) * 8 + e;
        } else if (j < 90) {
            int jj = j - 60; int h = jj / 5, e = jj - 5 * h;
            sc_idx[t] = (h * 5 + e) * 36 + s0;
        } else {
            sc_idx[t] = ((l15 - 10) * 5) * 36 + 33;
        }
    }
    float* vbase = &vT[0][0][0];
    __syncthreads();

    for (int p = 0; p < NP1; ++p) {
        const long node = (long)blockIdx.x * NP1 + p;
        const float* h1p = h1 + node * 480;
        const float* sfp = self_feat + node * 30;

        // ---- Phase A: rows 0..15 = h1, row 16 = self_feat, rest padding ----
        {
            float xv[8];
            if (si == 0) {
                int s = l15;
                #pragma unroll
                for (int i = 0; i < 8; ++i) {
                    int k = lq * 8 + i;
                    xv[i] = (k < 30) ? h1p[s * 30 + k] : 0.0f;
                }
            } else {
                #pragma unroll
                for (int i = 0; i < 8; ++i) {
                    int k = lq * 8 + i;
                    xv[i] = (l15 == 0 && k < 30) ? sfp[k] : 0.0f;
                }
            }
            int4v pk = { pack2_trunc(xv[0], xv[1]), pack2_trunc(xv[2], xv[3]),
                         pack2_trunc(xv[4], xv[5]), pack2_trunc(xv[6], xv[7]) };
            short8 af = __builtin_bit_cast(short8, pk);
            f32x4 c = {0.0f, 0.0f, 0.0f, 0.0f};
            c = __builtin_amdgcn_mfma_f32_16x16x32_bf16(af, blw, c, 0, 0, 0);
            #pragma unroll
            for (int r = 0; r < 4; ++r) {
                float yv = c[r] + lbv;
                yv = LRELU(yv);
                y_lds[si * 16 + lq * 4 + r][di * 16 + l15] = bftrunc(yv);
            }
        }
        __syncthreads();

        // ---- Phase B ----
        {
            short8 a0 = *(const short8*)&y_lds[l15][lq * 8];
            short8 a1 = *(const short8*)&y_lds[16 + l15][lq * 8];
            #pragma unroll
            for (int t = 0; t < 3; ++t) {
                short8 a = useA1[t] ? a1 : a0;
                f32x4 c = {0.0f, 0.0f, 0.0f, 0.0f};
                c = __builtin_amdgcn_mfma_f32_16x16x32_bf16(a, bfr[t], c, 0, 0, 0);
                float bias = sc_bias[t];
                if (!sc_isv[t]) {
                    short* pp = qk + sc_idx[t];
                    #pragma unroll
                    for (int r = 0; r < 4; ++r) pp[r * 8] = bftrunc(c[r] + bias);
                } else {
                    float* pp = vbase + sc_idx[t];
                    #pragma unroll
                    for (int r = 0; r < 4; ++r) pp[r] = c[r] + bias;
                }
            }
        }
        __syncthreads();

        // ---- Phase C: MFMA scores + masked softmax (valid t < 17) ----
        if (w < 3) {
            #pragma unroll
            for (int hh = 0; hh < 2; ++hh) {
                const int h = 2 * w + hh;
                short8 af = *(const short8*)&qk[((6 + h) * 33 + rowz) * 8];
                short8 bf = *(const short8*)&qk[(h * 33 + rowz) * 8];
                f32x16 c;
                #pragma unroll
                for (int r = 0; r < 16; ++r) c[r] = 0.0f;
                c = __builtin_amdgcn_mfma_f32_32x32x16_bf16(af, bf, c, 0, 0, 0);
                #pragma unroll
                for (int r = 0; r < 16; ++r) {
                    int tr = (r & 3) + 8 * (r >> 2) + 4 * h5;
                    c[r] = (tr < 17) ? c[r] : -1e30f;
                }
                float m = c[0];
                #pragma unroll
                for (int r = 1; r < 16; ++r) m = fmaxf(m, c[r]);
                m = fmaxf(m, __shfl_xor(m, 32));
                float Z = 0.0f;
                #pragma unroll
                for (int r = 0; r < 16; ++r) { c[r] = __expf(c[r] - m); Z += c[r]; }
                Z += __shfl_xor(Z, 32);
                float rZ = (1.0f / 17.0f) / Z;
                #pragma unroll
                for (int g = 0; g < 4; ++g) {
                    int tb = 8 * g + 4 * h5;
                    int2v wv;
                    wv.x = pack2_trunc(c[4 * g] * rZ, c[4 * g + 1] * rZ);
                    wv.y = pack2_trunc(c[4 * g + 2] * rZ, c[4 * g + 3] * rZ);
                    *(int2v*)&att2[h][scol][tb] = wv;
                }
            }
        }
        __syncthreads();

        // ---- Phase D: abar over valid s < 17, b32 pair reads ----
        if (tid < 96) {
            const int h = tid >> 4, tp = tid & 15;
            const short* cp = &att2[h][0][2 * tp];
            float s0 = 0.0f, s1 = 0.0f;
            #pragma unroll
            for (int s = 0; s < 17; ++s) {
                unsigned u = *(const unsigned*)(cp + s * 40);
                s0 += bflo(u);
                s1 += bfhi(u);
            }
            abar[h][2 * tp] = s0;
            abar[h][2 * tp + 1] = s1;
        }
        __syncthreads();

        // ---- Phase E ----
        if (tid < 240) {
            const int he = tid >> 3, tq = tid & 7;
            const int h = he / 5, e = he - 5 * h;
            f32x4 av = *(const f32x4*)&abar[h][tq * 4];
            f32x4 vv = *(const f32x4*)&vT[h][e][tq * 4];
            float part = av.x * vv.x + av.y * vv.y + av.z * vv.z + av.w * vv.w;
            part += __shfl_down(part, 4, 8);
            part += __shfl_down(part, 2, 8);
            part += __shfl_down(part, 1, 8);
            if (tq == 0) obar[he] = part;
        }
        __syncthreads();

        // ---- Phase F: emb ----
        if (tid < 240) {
            const int d = tid >> 3, jq = tid & 7;
            f32x4 ov = *(const f32x4*)&obar[jq * 4];
            float part = 0.0f;
            #pragma unroll
            for (int i = 0; i < 4; ++i) {
                int j = jq * 4 + i;
                if (j < 30) part = fmaf(ov[i], ow[d * 30 + j], part);
            }
            part += __shfl_down(part, 4, 8);
            part += __shfl_down(part, 2, 8);
            part += __shfl_down(part, 1, 8);
            if (jq == 0) embb[d] = part + ob[d];
        }
        __syncthreads();

        // ---- MLP 30 -> 64 -> 64 -> 2 + softmax ----
        {
            const int o = tid >> 2, kq = tid & 3;
            float part = 0.0f;
            #pragma unroll
            for (int i = 0; i < 8; ++i) {
                int k = kq * 8 + i;
                if (k < 30) part = fmaf(embb[k], cw1[o * 30 + k], part);
            }
            part += __shfl_down(part, 2, 4);
            part += __shfl_down(part, 1, 4);
            if (kq == 0) hb1[o] = LRELU(part + cb1[o]);
        }
        __syncthreads();
        {
            const int o = tid >> 2, kq = tid & 3;
            float part = 0.0f;
            #pragma unroll
            for (int i = 0; i < 16; ++i) {
                int k = kq * 16 + i;
                part = fmaf(hb1[k], cw2[o * 64 + k], part);
            }
            part += __shfl_down(part, 2, 4);
            part += __shfl_down(part, 1, 4);
            if (kq == 0) hb2[o] = LRELU(part + cb2[o]);
        }
        __syncthreads();
        if (tid < 128) {
            const int c = tid >> 6, k = tid & 63;
            float part = hb2[k] * cw3[c * 64 + k];
            part += __shfl_down(part, 32);
            part += __shfl_down(part, 16);
            part += __shfl_down(part, 8);
            part += __shfl_down(part, 4);
            part += __shfl_down(part, 2);
            part += __shfl_down(part, 1);
            if (k == 0) lg[c] = part + cb3[c];
        }
        __syncthreads();
        if (tid < 2) {
            float m = fmaxf(lg[0], lg[1]);
            float e0 = __expf(lg[0] - m), e1 = __expf(lg[1] - m);
            float pr = ((tid == 0) ? e0 : e1) / (e0 + e1);
            out[node * 2 + tid] = pr;
        }
        __syncthreads();
    }
}

extern "C" void kernel_launch(void* const* d_in, const int* in_sizes, int n_in,
                              void* d_out, int out_size, void* d_ws, size_t ws_size,
                              hipStream_t stream)
{
    const float* x2        = (const float*)d_in[0];
    const float* self_feat = (const float*)d_in[1];
    const float* lin_w2 = (const float*)d_in[2];
    const float* lin_b2 = (const float*)d_in[3];
    const float* in_w2  = (const float*)d_in[4];
    const float* in_b2  = (const float*)d_in[5];
    const float* out_w2 = (const float*)d_in[6];
    const float* out_b2 = (const float*)d_in[7];
    const float* lin_w1 = (const float*)d_in[8];
    const float* lin_b1 = (const float*)d_in[9];
    const float* in_w1  = (const float*)d_in[10];
    const float* in_b1  = (const float*)d_in[11];
    const float* out_w1 = (const float*)d_in[12];
    const float* out_b1 = (const float*)d_in[13];
    const float* cw1 = (const float*)d_in[14];
    const float* cb1 = (const float*)d_in[15];
    const float* cw2 = (const float*)d_in[16];
    const float* cb2 = (const float*)d_in[17];
    const float* cw3 = (const float*)d_in[18];
    const float* cb3 = (const float*)d_in[19];
    float* outp = (float*)d_out;

    float* h1 = (float*)d_ws;   // 65536 * 30 floats = 7.86 MB

    gl2_kernel<<<(4096 * 16) / PAIRS, 256, 0, stream>>>(
        x2, lin_w2, lin_b2, in_w2, in_b2, out_w2, out_b2, h1);

    gl1_mlp_kernel<<<4096 / NP1, 256, 0, stream>>>(
        h1, self_feat, lin_w1, lin_b1, in_w1, in_b1, out_w1, out_b1,
        cw1, cb1, cw2, cb2, cw3, cb3, outp);
}